// Round 4
// baseline (594.816 us; speedup 1.0000x reference)
//
#include <hip/hip_runtime.h>
#include <math.h>
#include <stdint.h>

#define BATCH 64
#define N 128
#define DIM 64
#define ARR_CAP 640

typedef unsigned uint32x2_t __attribute__((ext_vector_type(2)));

// branchless monotone float->uint (order-preserving incl. +inf)
__device__ __forceinline__ unsigned monokey(float x) {
    unsigned b = __float_as_uint(x);
    return b ^ (unsigned)(((int)b >> 31) | (int)0x80000000u);
}
__device__ __forceinline__ float monoval(unsigned k) {
    unsigned b = (k & 0x80000000u) ? (k & 0x7FFFFFFFu) : ~k;
    return __uint_as_float(b);
}

__device__ __forceinline__ unsigned umin_(unsigned a, unsigned b) { return a < b ? a : b; }
__device__ __forceinline__ unsigned umax_(unsigned a, unsigned b) { return a > b ? a : b; }
__device__ __forceinline__ int rl_i(int v, int l) { return __builtin_amdgcn_readlane(v, l); }
__device__ __forceinline__ float rl_f(float v, int l) {
    return __int_as_float(__builtin_amdgcn_readlane(__float_as_int(v), l));
}

#define DPP_ROR(x, n) __builtin_amdgcn_update_dpp((int)(x), (int)(x), 0x120 + (n), 0xF, 0xF, false)

__device__ __forceinline__ unsigned partner16(unsigned x) {
#if __has_builtin(__builtin_amdgcn_permlane16_swap)
    uint32x2_t r = __builtin_amdgcn_permlane16_swap(x, x, false, false);
    return umin_(r[0], r[1]);
#else
    return umin_(x, (unsigned)__shfl_xor((int)x, 16));
#endif
}
__device__ __forceinline__ unsigned partner32(unsigned x) {
#if __has_builtin(__builtin_amdgcn_permlane32_swap)
    uint32x2_t r = __builtin_amdgcn_permlane32_swap(x, x, false, false);
    return umin_(r[0], r[1]);
#else
    return umin_(x, (unsigned)__shfl_xor((int)x, 32));
#endif
}

// full-wave min of packed keys; every lane gets the result. VALU-only.
__device__ __forceinline__ unsigned wave_kmin(unsigned k) {
    unsigned a = (unsigned)DPP_ROR(k, 1);
    unsigned b = (unsigned)DPP_ROR(k, 2);
    k = umin_(k, umin_(a, b));            // 0..2
    a = (unsigned)DPP_ROR(k, 3);
    b = (unsigned)DPP_ROR(k, 6);
    k = umin_(k, umin_(a, b));            // 0..8
    a = (unsigned)DPP_ROR(k, 9);
    k = umin_(k, a);                      // 0..15 (wrap overlap OK for min)
    k = partner16(k);
    k = partner32(k);
    return k;
}

// two smallest keys across the wave (disjoint-window rotate-reduce). ks<=kb kept.
__device__ __forceinline__ void wave_kmin2(unsigned& ks, unsigned& kb, int lane) {
    unsigned ps, pb;
#define KM2_COMBINE { unsigned ns = umin_(ks, ps); kb = umin_(umin_(kb, pb), umax_(ks, ps)); ks = ns; }
#define KM2_SWAP16 { \
    uint32x2_t rs = __builtin_amdgcn_permlane16_swap(ks, ks, false, false); \
    uint32x2_t rb = __builtin_amdgcn_permlane16_swap(kb, kb, false, false); \
    ps = (lane & 16) ? rs[0] : rs[1]; pb = (lane & 16) ? rb[0] : rb[1]; }
#define KM2_SWAP32 { \
    uint32x2_t rs = __builtin_amdgcn_permlane32_swap(ks, ks, false, false); \
    uint32x2_t rb = __builtin_amdgcn_permlane32_swap(kb, kb, false, false); \
    ps = (lane & 32) ? rs[0] : rs[1]; pb = (lane & 32) ? rb[0] : rb[1]; }
    ps = (unsigned)DPP_ROR(ks, 1); pb = (unsigned)DPP_ROR(kb, 1); KM2_COMBINE;
    ps = (unsigned)DPP_ROR(ks, 2); pb = (unsigned)DPP_ROR(kb, 2); KM2_COMBINE;
    ps = (unsigned)DPP_ROR(ks, 4); pb = (unsigned)DPP_ROR(kb, 4); KM2_COMBINE;
    ps = (unsigned)DPP_ROR(ks, 8); pb = (unsigned)DPP_ROR(kb, 8); KM2_COMBINE;
#if __has_builtin(__builtin_amdgcn_permlane16_swap)
    KM2_SWAP16; KM2_COMBINE;
#else
    ps = (unsigned)__shfl_xor((int)ks, 16); pb = (unsigned)__shfl_xor((int)kb, 16); KM2_COMBINE;
#endif
#if __has_builtin(__builtin_amdgcn_permlane32_swap)
    KM2_SWAP32; KM2_COMBINE;
#else
    ps = (unsigned)__shfl_xor((int)ks, 32); pb = (unsigned)__shfl_xor((int)kb, 32); KM2_COMBINE;
#endif
#undef KM2_COMBINE
#undef KM2_SWAP16
#undef KM2_SWAP32
}

// One block = one batch, 64 threads (1 wave). Lane owns 1-based columns ja=lane+1, jb=lane+65.
// Column state (p, u[p]) and way[] live in the owner lane's registers; all cross-column
// access is wave-uniform -> v_readlane. No LDS traffic in the solve except dist rows.
__global__ __launch_bounds__(64, 1)
void lsap_kernel(const float* __restrict__ y_true, const float* __restrict__ y_pred,
                 float* __restrict__ batch_sums, float* __restrict__ out, int use_atomic) {
    __shared__ float dist[N * N];            // 64 KB; columns ca/cb read only by owner lane
    __shared__ float ytl[N * DIM];           // 32 KB
    __shared__ int unlist[N + ARR_CAP + 8];  // free-row queue

    const int b = blockIdx.x;
    const int lane = threadIdx.x;
    const int ca = lane, cb = lane + 64;
    const int ja = lane + 1, jb = lane + 65;

    // ---- stage y_true[b] into LDS ----
    {
        const float4* yt4 = (const float4*)(y_true + (size_t)b * N * DIM);
        float4* ytl4 = (float4*)ytl;
        for (int k = lane; k < N * DIM / 4; k += 64) ytl4[k] = yt4[k];
    }

    // ---- y_pred rows ca, cb into registers ----
    float ypa[DIM], ypb[DIM];
    {
        const float4* pa4 = (const float4*)(y_pred + (size_t)b * N * DIM + (size_t)ca * DIM);
        const float4* pb4 = (const float4*)(y_pred + (size_t)b * N * DIM + (size_t)cb * DIM);
        #pragma unroll
        for (int k = 0; k < DIM / 4; ++k) {
            float4 v4 = pa4[k];
            ypa[4*k+0]=v4.x; ypa[4*k+1]=v4.y; ypa[4*k+2]=v4.z; ypa[4*k+3]=v4.w;
            float4 w4 = pb4[k];
            ypb[4*k+0]=w4.x; ypb[4*k+1]=w4.y; ypb[4*k+2]=w4.z; ypb[4*k+3]=w4.w;
        }
    }
    __syncthreads();   // ytl visible

    // ---- Phase A: dist columns + column minima (v init) ----
    float va = INFINITY, vb = INFINITY;      // v[ja], v[jb]
    for (int i = 0; i < N; ++i) {
        const float4* yr = (const float4*)(ytl + i * DIM);
        float a0 = 0.f, a1 = 0.f;
        #pragma unroll
        for (int k = 0; k < DIM / 4; ++k) {
            float4 t4 = yr[k];
            float d;
            d = t4.x - ypa[4*k+0]; a0 = fmaf(d, d, a0);
            d = t4.y - ypa[4*k+1]; a0 = fmaf(d, d, a0);
            d = t4.z - ypa[4*k+2]; a0 = fmaf(d, d, a0);
            d = t4.w - ypa[4*k+3]; a0 = fmaf(d, d, a0);
            d = t4.x - ypb[4*k+0]; a1 = fmaf(d, d, a1);
            d = t4.y - ypb[4*k+1]; a1 = fmaf(d, d, a1);
            d = t4.z - ypb[4*k+2]; a1 = fmaf(d, d, a1);
            d = t4.w - ypb[4*k+3]; a1 = fmaf(d, d, a1);
        }
        float d0 = sqrtf(a0), d1 = sqrtf(a1);
        dist[i * N + ca] = d0;
        dist[i * N + cb] = d1;
        va = fminf(va, d0);
        vb = fminf(vb, d1);
    }

    // Column state in registers: p (0 = free) and u[p] for each owned column.
    int   pa = 0, pb = 0;
    float upa = 0.f, upb = 0.f;
    float ura = 0.f, urb = 0.f;              // u_row for rows lane / lane+64
    int   waya = 0, wayb = 0;

    // ---- Phase B+C: row minima (kmin2) + greedy assignment with reduction transfer ----
    int nun = 0;
    for (int r = 0; r < N; ++r) {
        float c0 = dist[r * N + ca] - va;
        float c1 = dist[r * N + cb] - vb;
        unsigned k0 = (monokey(c0) & ~0x7Fu) | (unsigned)lane;          // col bit 0 -> ja
        unsigned k1 = (monokey(c1) & ~0x7Fu) | 64u | (unsigned)lane;    // col bit 1 -> jb
        unsigned ks = umin_(k0, k1), kb2 = umax_(k0, k1);
        wave_kmin2(ks, kb2, lane);
        int s1 = __builtin_amdgcn_readfirstlane((int)ks);
        int s2 = __builtin_amdgcn_readfirstlane((int)kb2);
        float u1 = monoval((unsigned)s1 & ~0x7Fu);
        float u2 = monoval((unsigned)s2 & ~0x7Fu);
        int w1 = s1 & 63, cb1 = (s1 >> 6) & 1;
        int j1 = 1 + w1 + (cb1 << 6);
        int pj1 = rl_i(cb1 ? pb : pa, w1);
        if (pj1 == 0) {
            float dd = u2 - u1;              // reduction transfer
            if (ja == j1) { pa = r + 1; upa = u2; va -= dd; }
            if (jb == j1) { pb = r + 1; upb = u2; vb -= dd; }
            if ((r & 63) == lane) { if (r < 64) ura = u2; else urb = u2; }
        } else {
            unlist[nun] = r;                 // all lanes write same value
            ++nun;
            if ((r & 63) == lane) { if (r < 64) ura = u1; else urb = u1; }
        }
    }

    // ---- Augmenting row reduction (LAPJV), op-capped, LDS-free except dist rows ----
    int k = 0, nf = nun, ops = 0, pending = -1;
    int unext = unlist[0];
    while (ops < ARR_CAP) {
        int i;
        if (pending >= 0) { i = pending; pending = -1; }
        else if (k < nf) { i = unext; ++k; unext = unlist[k]; }
        else break;
        ++ops;

        float c0 = dist[i * N + ca] - va;
        float c1 = dist[i * N + cb] - vb;
        unsigned k0 = (monokey(c0) & ~0x7Fu) | (unsigned)lane;
        unsigned k1 = (monokey(c1) & ~0x7Fu) | 64u | (unsigned)lane;
        unsigned ks = umin_(k0, k1), kb2 = umax_(k0, k1);
        wave_kmin2(ks, kb2, lane);
        int s1 = __builtin_amdgcn_readfirstlane((int)ks);
        int s2 = __builtin_amdgcn_readfirstlane((int)kb2);
        float u1 = monoval((unsigned)s1 & ~0x7Fu);
        float u2 = monoval((unsigned)s2 & ~0x7Fu);
        int w1 = s1 & 63, cb1 = (s1 >> 6) & 1;
        int w2 = s2 & 63, cb2 = (s2 >> 6) & 1;
        int j1 = 1 + w1 + (cb1 << 6);
        int j2 = 1 + w2 + (cb2 << 6);
        int pj1 = rl_i(cb1 ? pb : pa, w1);
        int pj2 = rl_i(cb2 ? pb : pa, w2);

        int jt, it0;
        if (u1 < u2) {
            float dd = u2 - u1;
            if (ja == j1) va -= dd;
            if (jb == j1) vb -= dd;
            jt = j1; it0 = pj1;
        } else if (pj1 > 0) { jt = j2; it0 = pj2; }
        else { jt = j1; it0 = 0; }

        if (ja == jt) { pa = i + 1; upa = u2; }
        if (jb == jt) { pb = i + 1; upb = u2; }
        if ((i & 63) == lane) { if (i < 64) ura = u2; else urb = u2; }

        if (it0 > 0) {
            if (u1 < u2) pending = it0 - 1;
            else {
                unlist[nf] = it0 - 1;
                if (k == nf) unext = it0 - 1;   // keep prefetch invariant
                ++nf;
            }
        }
    }
    if (pending >= 0) { --k; unlist[k] = pending; }

    // ---- Dijkstra augmenting phases for remaining free rows ----
    for (int t = k; t < nf; ++t) {
        int r = unlist[t];
        float u_i = rl_f((r >= 64) ? urb : ura, r & 63);
        float mina = INFINITY, minb = INFINITY;
        int useda = 0, usedb = 0;
        waya = 0; wayb = 0;
        float uacca = 0.f, uaccb = 0.f;
        float u_acc_i = u_i;
        int j0 = 0, i0 = r + 1;
        float u0c = u_i;

        for (int it = 0; it < N + 1; ++it) {
            if (ja == j0) useda = 1;
            if (jb == j0) usedb = 1;
            const float* drow = dist + (i0 - 1) * N;
            float d0 = drow[ca], d1 = drow[cb];
            if (!useda) { float cur = d0 - u0c - va; if (cur < mina) { mina = cur; waya = j0; } }
            if (!usedb) { float cur = d1 - u0c - vb; if (cur < minb) { minb = cur; wayb = j0; } }

            float candA = useda ? INFINITY : mina;
            float candB = usedb ? INFINITY : minb;
            unsigned kA = (monokey(candA) & ~0x7Fu) | (unsigned)lane;
            unsigned kB = (monokey(candB) & ~0x7Fu) | 64u | (unsigned)lane;
            unsigned kk = wave_kmin(umin_(kA, kB));
            int s = __builtin_amdgcn_readfirstlane((int)kk);
            float delta = monoval((unsigned)s & ~0x7Fu);
            int w = s & 63, cbw = (s >> 6) & 1;
            int j1 = 1 + w + (cbw << 6);
            int i1 = rl_i(cbw ? pb : pa, w);
            float u1v = rl_f(cbw ? upb : upa, w);

            if (useda) { va -= delta; uacca += delta; } else { mina -= delta; }
            if (usedb) { vb -= delta; uaccb += delta; } else { minb -= delta; }
            u_acc_i += delta;

            j0 = j1;
            if (i1 == 0) break;
            i0 = i1; u0c = u1v;
        }

        // deferred dual updates for used columns (registers)
        if (useda) upa += uacca;
        if (usedb) upb += uaccb;

        // ---- augment: register readlane chase (all lanes, uniform) ----
        int jj = j0;
        for (int hop = 0; hop < N + 1; ++hop) {
            int wj = (jj - 1) & 63;
            int sbj = (jj > 64) ? 1 : 0;
            int jp = rl_i(sbj ? wayb : waya, wj);
            int np; float nu;
            if (jp == 0) { np = r + 1; nu = u_acc_i; }
            else {
                int wp = (jp - 1) & 63;
                int sbp = (jp > 64) ? 1 : 0;
                np = rl_i(sbp ? pb : pa, wp);
                nu = rl_f(sbp ? upb : upa, wp);
            }
            if (ja == jj) { pa = np; upa = nu; }
            if (jb == jj) { pb = np; upb = nu; }
            if (jp == 0) break;
            jj = jp;
        }
    }

    // ---- matched sum ----
    float s = dist[(pa - 1) * N + ca] + dist[(pb - 1) * N + cb];
    #pragma unroll
    for (int m = 1; m < 64; m <<= 1) s += __shfl_xor(s, m);
    if (lane == 0) {
        if (use_atomic) atomicAdd(out, s * (1.0f / (float)BATCH));
        else batch_sums[b] = s;
    }
}

__global__ __launch_bounds__(64)
void reduce_kernel(const float* __restrict__ bs, float* __restrict__ out) {
    int tid = threadIdx.x;
    float v = bs[tid];
    #pragma unroll
    for (int m = 1; m < 64; m <<= 1) v += __shfl_xor(v, m);
    if (tid == 0) out[0] = v * (1.0f / (float)BATCH);
}

extern "C" void kernel_launch(void* const* d_in, const int* in_sizes, int n_in,
                              void* d_out, int out_size, void* d_ws, size_t ws_size,
                              hipStream_t stream) {
    const float* y_true = (const float*)d_in[0];
    const float* y_pred = (const float*)d_in[1];
    float* out = (float*)d_out;

    if (ws_size >= BATCH * sizeof(float)) {
        float* bs = (float*)d_ws;
        lsap_kernel<<<BATCH, 64, 0, stream>>>(y_true, y_pred, bs, out, 0);
        reduce_kernel<<<1, 64, 0, stream>>>(bs, out);
    } else {
        hipMemsetAsync(d_out, 0, sizeof(float), stream);
        lsap_kernel<<<BATCH, 64, 0, stream>>>(y_true, y_pred, nullptr, out, 1);
    }
}